// Round 2
// baseline (295.151 us; speedup 1.0000x reference)
//
#include <hip/hip_runtime.h>

#define B_ 2
#define N_ 2048
#define F_ 64
#define C_ 64
#define L_ 4
#define SK 4    // split-K factor over j: 4 blocks/CU for latency decorrelation
#define NJ (N_ / SK)        // 512 j per block
#define TSTEPS (NJ / 32)    // 16 K-steps
#define PJ 40   // padded LDS j-stride (halves): 80 B rows -> 16B-aligned b128 reads, ~2-way banks

typedef _Float16 half8 __attribute__((ext_vector_type(8)));
typedef _Float16 half2 __attribute__((ext_vector_type(2)));
typedef float floatx4 __attribute__((ext_vector_type(4)));

// ---------------------------------------------------------------------------
// K0: V[b][j][f] -> Vth[b][f][j] (fp16) and Vt32[b][f][j] (fp32), LDS transpose
// grid = B * N/64 = 64 blocks, 256 threads
// ---------------------------------------------------------------------------
__global__ __launch_bounds__(256) void k0_transpose(const float* __restrict__ V,
                                                    _Float16* __restrict__ Vth,
                                                    float* __restrict__ Vt32) {
    __shared__ float tile[64][65];
    const int b  = blockIdx.x >> 5;          // 0..1
    const int j0 = (blockIdx.x & 31) * 64;   // j tile base
    const int tid = threadIdx.x;

    const floatx4* V4 = (const floatx4*)(V + ((size_t)(b * N_ + j0)) * F_);
#pragma unroll
    for (int s = 0; s < 4; ++s) {
        int g = tid + 256 * s;               // 0..1023 float4 slots
        int jl = g >> 4;                     // 0..63
        int fq = g & 15;                     // 0..15
        floatx4 v = V4[jl * 16 + fq];
        tile[jl][fq * 4 + 0] = v.x;
        tile[jl][fq * 4 + 1] = v.y;
        tile[jl][fq * 4 + 2] = v.z;
        tile[jl][fq * 4 + 3] = v.w;
    }
    __syncthreads();

    const int f = tid >> 2;                  // 0..63
    const int jb = (tid & 3) * 16;           // 0..48
    _Float16* dh = Vth  + ((size_t)(b * F_ + f)) * N_ + j0 + jb;
    float*    df = Vt32 + ((size_t)(b * F_ + f)) * N_ + j0 + jb;
#pragma unroll
    for (int u = 0; u < 16; u += 4) {
        float x0 = tile[jb + u + 0][f];
        float x1 = tile[jb + u + 1][f];
        float x2 = tile[jb + u + 2][f];
        float x3 = tile[jb + u + 3][f];
        floatx4 w = {x0, x1, x2, x3};
        *(floatx4*)(df + u) = w;
        half2 h01 = {(_Float16)x0, (_Float16)x1};   // RNE conversion
        half2 h23 = {(_Float16)x2, (_Float16)x3};
        *(half2*)(dh + u + 0) = h01;
        *(half2*)(dh + u + 2) = h23;
    }
}

// ---------------------------------------------------------------------------
// K1: fused deg + agg via fp16 MFMA, split-K over j.
// grid = B * N/16 * SK = 1024 blocks (4/CU), 256 thr (4 waves).
// Block: 16 i-rows, j in [p*NJ, (p+1)*NJ); wave w handles edge type l = w.
// A staged fp32->fp16 into double-buffered LDS (depth-2 reg prefetch);
// V fragments prefetched to registers from Vth (L2-hot).
// Writes partial aggT[p][b][k=l*64+f][i] (fp32) and degT[p][b][l][i].
// ---------------------------------------------------------------------------
__global__ __launch_bounds__(256, 4) void k1_agg(const float* __restrict__ A,
                                                 const _Float16* __restrict__ Vth,
                                                 float* __restrict__ aggT,
                                                 float* __restrict__ degT) {
    __shared__ _Float16 lds[2 * 4 * 16 * PJ];   // 10 KB: [buf][l][i][PJ]

    const int bid = blockIdx.x;          // 0..1023
    const int b   = bid >> 9;
    const int rem = bid & 511;
    const int i0  = (rem >> 2) * 16;
    const int p   = rem & 3;             // split-K slice
    const int tid  = threadIdx.x;
    const int w    = tid >> 6;       // wave id == l
    const int lane = tid & 63;
    const int m    = lane & 15;      // A row / B col / C col within tile
    const int q    = lane >> 4;      // quad group

    // staging mapping: thread -> (row i_s, j-pair jp)
    const int i_s = tid >> 4;        // 0..15
    const int jp  = tid & 15;        // 0..15 -> j = 2jp, 2jp+1

    // A row (b,i): N_ float4s (each j -> 4 l's); this block's slice starts at j = p*NJ
    const floatx4* Abase = (const floatx4*)A + ((size_t)(b * N_ + i0 + i_s)) * N_ + p * NJ;
    const _Float16* Vrow = Vth + ((size_t)b * F_) * N_ + p * NJ;

    floatx4 acc0 = {0,0,0,0}, acc1 = {0,0,0,0}, acc2 = {0,0,0,0}, acc3 = {0,0,0,0};
    floatx4 accd = {0,0,0,0};

    half8 bones;                     // B[k][0] = 1 -> col 0 of deg tile = row sums
#pragma unroll
    for (int e = 0; e < 8; ++e) bones[e] = (m == 0) ? (_Float16)1.0f : (_Float16)0.0f;

    floatx4 a_cur0, a_cur1, a_nxt0, a_nxt1;
    half8 v_cur0, v_cur1, v_cur2, v_cur3, v_nxt0, v_nxt1, v_nxt2, v_nxt3;

#define LOAD_A(t, x0, x1) do { int jj = (t) * 32 + 2 * jp; x0 = Abase[jj]; x1 = Abase[jj + 1]; } while (0)
#define LOAD_V(t, v0, v1, v2, v3) do { int jj = (t) * 32 + q * 8;                                  \
        v0 = *(const half8*)(Vrow + (size_t)(0  + m) * N_ + jj);                                   \
        v1 = *(const half8*)(Vrow + (size_t)(16 + m) * N_ + jj);                                   \
        v2 = *(const half8*)(Vrow + (size_t)(32 + m) * N_ + jj);                                   \
        v3 = *(const half8*)(Vrow + (size_t)(48 + m) * N_ + jj); } while (0)

    LOAD_A(0, a_cur0, a_cur1);
    LOAD_V(0, v_cur0, v_cur1, v_cur2, v_cur3);
    LOAD_A(1, a_nxt0, a_nxt1);
    LOAD_V(1, v_nxt0, v_nxt1, v_nxt2, v_nxt3);

#pragma unroll 2
    for (int t = 0; t < TSTEPS; ++t) {
        const int buf = t & 1;
        _Float16* dst = lds + buf * (4 * 16 * PJ);
        {   // fp32 -> fp16 (RNE) + LDS write: lane holds A[i_s][2jp..2jp+1][l=0..3]
            const float* c0 = (const float*)&a_cur0;
            const float* c1 = (const float*)&a_cur1;
#pragma unroll
            for (int l = 0; l < 4; ++l) {
                half2 h = {(_Float16)c0[l], (_Float16)c1[l]};
                *(half2*)(dst + (l * 16 + i_s) * PJ + 2 * jp) = h;
            }
        }
        __syncthreads();

        // rotate prefetch (depth 2: tile t+2 issued now, consumed at iter t+2)
        a_cur0 = a_nxt0; a_cur1 = a_nxt1;
        const int tn = (t + 2 < TSTEPS) ? (t + 2) : (TSTEPS - 1);
        LOAD_A(tn, a_nxt0, a_nxt1);

        // compute: A-frag from LDS plane l=w, B-frags from registers
        half8 af = *(const half8*)(lds + buf * (4 * 16 * PJ) + (w * 16 + m) * PJ + q * 8);
        acc0 = __builtin_amdgcn_mfma_f32_16x16x32_f16(af, v_cur0, acc0, 0, 0, 0);
        acc1 = __builtin_amdgcn_mfma_f32_16x16x32_f16(af, v_cur1, acc1, 0, 0, 0);
        acc2 = __builtin_amdgcn_mfma_f32_16x16x32_f16(af, v_cur2, acc2, 0, 0, 0);
        acc3 = __builtin_amdgcn_mfma_f32_16x16x32_f16(af, v_cur3, acc3, 0, 0, 0);
        accd = __builtin_amdgcn_mfma_f32_16x16x32_f16(af, bones,  accd, 0, 0, 0);

        v_cur0 = v_nxt0; v_cur1 = v_nxt1; v_cur2 = v_nxt2; v_cur3 = v_nxt3;
        LOAD_V(tn, v_nxt0, v_nxt1, v_nxt2, v_nxt3);
    }
#undef LOAD_A
#undef LOAD_V

    // epilogue: C layout col=lane&15 (f), row=q*4+reg (i) -> aligned float4 stores
    float* aggb = aggT + ((size_t)(p * B_ + b)) * 256 * N_;
    const int ibase = i0 + q * 4;
    {
        int k = w * 64 + 0  + m; *(floatx4*)(aggb + (size_t)k * N_ + ibase) = acc0;
    }
    {
        int k = w * 64 + 16 + m; *(floatx4*)(aggb + (size_t)k * N_ + ibase) = acc1;
    }
    {
        int k = w * 64 + 32 + m; *(floatx4*)(aggb + (size_t)k * N_ + ibase) = acc2;
    }
    {
        int k = w * 64 + 48 + m; *(floatx4*)(aggb + (size_t)k * N_ + ibase) = acc3;
    }
    if (m == 0) {
        *(floatx4*)(degT + ((size_t)((p * B_ + b) * L_ + w)) * N_ + ibase) = accd;
    }
}

// ---------------------------------------------------------------------------
// K2: out[b,i,c] = sigmoid(V@w1 + (deg (x) V)@w2 - agg@w3), fp32 VALU.
// Sums the SK split-K partials of agg/deg inline.
// grid = B * N/16 = 256 blocks, 256 threads; thread = (i_local, 4 c's).
// ---------------------------------------------------------------------------
__global__ __launch_bounds__(256) void k2_out(const float* __restrict__ Vt32,
                                              const float* __restrict__ degT,
                                              const float* __restrict__ aggT,
                                              const float* __restrict__ w1,
                                              const float* __restrict__ w2,
                                              const float* __restrict__ w3,
                                              float* __restrict__ out) {
    const int bid = blockIdx.x;
    const int b   = bid >> 7;
    const int i0  = (bid & 127) * 16;
    const int tid = threadIdx.x;
    const int il  = tid & 15;
    const int cg  = tid >> 4;            // c = cg*4 .. cg*4+3
    const int i   = i0 + il;

    const size_t PS_AGG = (size_t)B_ * 256 * N_;   // stride between agg partials
    const size_t PS_DEG = (size_t)B_ * L_ * N_;    // stride between deg partials

    const float* Vb = Vt32 + (size_t)b * F_ * N_;
    const float* db = degT + (size_t)b * L_ * N_;
    const float* gb = aggT + (size_t)b * 256 * N_;

    floatx4 acc = {0, 0, 0, 0};

    // term1: V @ w1
#pragma unroll 4
    for (int f = 0; f < 64; ++f) {
        float x = Vb[(size_t)f * N_ + i];
        floatx4 wv = *(const floatx4*)(w1 + f * 64 + cg * 4);
        acc += x * wv;
    }
    // term2: (deg (x) V) @ w2, k = l*64 + f
#pragma unroll
    for (int l = 0; l < 4; ++l) {
        float dl = 0.0f;
#pragma unroll
        for (int pp = 0; pp < SK; ++pp) dl += db[(size_t)l * N_ + i + pp * PS_DEG];
#pragma unroll 4
        for (int f = 0; f < 64; ++f) {
            float x = dl * Vb[(size_t)f * N_ + i];
            floatx4 wv = *(const floatx4*)(w2 + (l * 64 + f) * 64 + cg * 4);
            acc += x * wv;
        }
    }
    // term3: agg @ w3 (minus), summing SK partials
#pragma unroll 2
    for (int k = 0; k < 256; ++k) {
        const float* g = gb + (size_t)k * N_ + i;
        float x = g[0] + g[PS_AGG] + g[2 * PS_AGG] + g[3 * PS_AGG];
        floatx4 wv = *(const floatx4*)(w3 + k * 64 + cg * 4);
        acc -= x * wv;
    }

    floatx4 r;
#pragma unroll
    for (int e = 0; e < 4; ++e) r[e] = 1.0f / (1.0f + __expf(-acc[e]));
    *(floatx4*)(out + ((size_t)(b * N_ + i)) * C_ + cg * 4) = r;
}

// ---------------------------------------------------------------------------
extern "C" void kernel_launch(void* const* d_in, const int* in_sizes, int n_in,
                              void* d_out, int out_size, void* d_ws, size_t ws_size,
                              hipStream_t stream) {
    const float* V  = (const float*)d_in[0];
    const float* A  = (const float*)d_in[1];
    const float* w1 = (const float*)d_in[2];
    const float* w2 = (const float*)d_in[3];
    const float* w3 = (const float*)d_in[4];
    float* out = (float*)d_out;

    char* ws = (char*)d_ws;
    float*    aggT = (float*)(ws);                  // SK*2*256*2048*4 = 16 MB
    float*    degT = (float*)(ws + 16777216);       // SK*2*4*2048*4   = 256 KB
    _Float16* Vth  = (_Float16*)(ws + 17039360);    // 2*64*2048*2     = 512 KB
    float*    Vt32 = (float*)(ws + 17563648);       // 2*64*2048*4     = 1 MB

    hipLaunchKernelGGL(k0_transpose, dim3(B_ * (N_ / 64)), dim3(256), 0, stream, V, Vth, Vt32);
    hipLaunchKernelGGL(k1_agg,       dim3(B_ * (N_ / 16) * SK), dim3(256), 0, stream, A, Vth, aggT, degT);
    hipLaunchKernelGGL(k2_out,       dim3(B_ * (N_ / 16)), dim3(256), 0, stream, Vt32, degT, aggT,
                       w1, w2, w3, out);
}

// Round 4
// 243.162 us; speedup vs baseline: 1.2138x; 1.2138x over previous
//
#include <hip/hip_runtime.h>

#define B_ 2
#define N_ 2048
#define F_ 64
#define C_ 64
#define L_ 4
#define SK 4    // split-K factor over j: 4 blocks/CU for latency decorrelation
#define NJ (N_ / SK)        // 512 j per block
#define TSTEPS (NJ / 32)    // 16 K-steps
#define PJ 40   // padded LDS j-stride (halves): 80 B rows -> 16B-aligned b128 reads, ~2-way banks

typedef _Float16 half8 __attribute__((ext_vector_type(8)));
typedef _Float16 half2 __attribute__((ext_vector_type(2)));
typedef float floatx4 __attribute__((ext_vector_type(4)));

// ---------------------------------------------------------------------------
// K0: V[b][j][f] -> Vth[b][f][j] (fp16), LDS transpose.
// grid = B * N/64 = 64 blocks, 256 threads
// ---------------------------------------------------------------------------
__global__ __launch_bounds__(256) void k0_transpose(const float* __restrict__ V,
                                                    _Float16* __restrict__ Vth) {
    __shared__ float tile[64][65];
    const int b  = blockIdx.x >> 5;          // 0..1
    const int j0 = (blockIdx.x & 31) * 64;   // j tile base
    const int tid = threadIdx.x;

    const floatx4* V4 = (const floatx4*)(V + ((size_t)(b * N_ + j0)) * F_);
#pragma unroll
    for (int s = 0; s < 4; ++s) {
        int g = tid + 256 * s;               // 0..1023 float4 slots
        int jl = g >> 4;                     // 0..63
        int fq = g & 15;                     // 0..15
        floatx4 v = V4[jl * 16 + fq];
        tile[jl][fq * 4 + 0] = v.x;
        tile[jl][fq * 4 + 1] = v.y;
        tile[jl][fq * 4 + 2] = v.z;
        tile[jl][fq * 4 + 3] = v.w;
    }
    __syncthreads();

    const int f = tid >> 2;                  // 0..63
    const int jb = (tid & 3) * 16;           // 0..48
    _Float16* dh = Vth + ((size_t)(b * F_ + f)) * N_ + j0 + jb;
#pragma unroll
    for (int u = 0; u < 16; u += 4) {
        half2 h01 = {(_Float16)tile[jb + u + 0][f], (_Float16)tile[jb + u + 1][f]};   // RNE
        half2 h23 = {(_Float16)tile[jb + u + 2][f], (_Float16)tile[jb + u + 3][f]};
        *(half2*)(dh + u + 0) = h01;
        *(half2*)(dh + u + 2) = h23;
    }
}

// ---------------------------------------------------------------------------
// K1: fused deg + agg via fp16 MFMA, split-K over j.  VERBATIM round-2 kernel
// (hardware-verified: passed absmax 3.9e-3).
// grid = B * N/16 * SK = 1024 blocks (4/CU), 256 thr (4 waves).
// Writes partial aggT[p][b][k=l*64+f][i] (fp32) and degT[p][b][l][i].
// ---------------------------------------------------------------------------
__global__ __launch_bounds__(256, 4) void k1_agg(const float* __restrict__ A,
                                                 const _Float16* __restrict__ Vth,
                                                 float* __restrict__ aggT,
                                                 float* __restrict__ degT) {
    __shared__ _Float16 lds[2 * 4 * 16 * PJ];   // 10 KB: [buf][l][i][PJ]

    const int bid = blockIdx.x;          // 0..1023
    const int b   = bid >> 9;
    const int rem = bid & 511;
    const int i0  = (rem >> 2) * 16;
    const int p   = rem & 3;             // split-K slice
    const int tid  = threadIdx.x;
    const int w    = tid >> 6;       // wave id == l
    const int lane = tid & 63;
    const int m    = lane & 15;      // A row / B col / C col within tile
    const int q    = lane >> 4;      // quad group

    // staging mapping: thread -> (row i_s, j-pair jp)
    const int i_s = tid >> 4;        // 0..15
    const int jp  = tid & 15;        // 0..15 -> j = 2jp, 2jp+1

    const floatx4* Abase = (const floatx4*)A + ((size_t)(b * N_ + i0 + i_s)) * N_ + p * NJ;
    const _Float16* Vrow = Vth + ((size_t)b * F_) * N_ + p * NJ;

    floatx4 acc0 = {0,0,0,0}, acc1 = {0,0,0,0}, acc2 = {0,0,0,0}, acc3 = {0,0,0,0};
    floatx4 accd = {0,0,0,0};

    half8 bones;                     // B[k][0] = 1 -> col 0 of deg tile = row sums
#pragma unroll
    for (int e = 0; e < 8; ++e) bones[e] = (m == 0) ? (_Float16)1.0f : (_Float16)0.0f;

    floatx4 a_cur0, a_cur1, a_nxt0, a_nxt1;
    half8 v_cur0, v_cur1, v_cur2, v_cur3, v_nxt0, v_nxt1, v_nxt2, v_nxt3;

#define LOAD_A(t, x0, x1) do { int jj = (t) * 32 + 2 * jp; x0 = Abase[jj]; x1 = Abase[jj + 1]; } while (0)
#define LOAD_V(t, v0, v1, v2, v3) do { int jj = (t) * 32 + q * 8;                                  \
        v0 = *(const half8*)(Vrow + (size_t)(0  + m) * N_ + jj);                                   \
        v1 = *(const half8*)(Vrow + (size_t)(16 + m) * N_ + jj);                                   \
        v2 = *(const half8*)(Vrow + (size_t)(32 + m) * N_ + jj);                                   \
        v3 = *(const half8*)(Vrow + (size_t)(48 + m) * N_ + jj); } while (0)

    LOAD_A(0, a_cur0, a_cur1);
    LOAD_V(0, v_cur0, v_cur1, v_cur2, v_cur3);
    LOAD_A(1, a_nxt0, a_nxt1);
    LOAD_V(1, v_nxt0, v_nxt1, v_nxt2, v_nxt3);

#pragma unroll 2
    for (int t = 0; t < TSTEPS; ++t) {
        const int buf = t & 1;
        _Float16* dst = lds + buf * (4 * 16 * PJ);
        {   // fp32 -> fp16 (RNE) + LDS write: lane holds A[i_s][2jp..2jp+1][l=0..3]
            const float* c0 = (const float*)&a_cur0;
            const float* c1 = (const float*)&a_cur1;
#pragma unroll
            for (int l = 0; l < 4; ++l) {
                half2 h = {(_Float16)c0[l], (_Float16)c1[l]};
                *(half2*)(dst + (l * 16 + i_s) * PJ + 2 * jp) = h;
            }
        }
        __syncthreads();

        // rotate prefetch (depth 2: tile t+2 issued now, consumed at iter t+2)
        a_cur0 = a_nxt0; a_cur1 = a_nxt1;
        const int tn = (t + 2 < TSTEPS) ? (t + 2) : (TSTEPS - 1);
        LOAD_A(tn, a_nxt0, a_nxt1);

        // compute: A-frag from LDS plane l=w, B-frags from registers
        half8 af = *(const half8*)(lds + buf * (4 * 16 * PJ) + (w * 16 + m) * PJ + q * 8);
        acc0 = __builtin_amdgcn_mfma_f32_16x16x32_f16(af, v_cur0, acc0, 0, 0, 0);
        acc1 = __builtin_amdgcn_mfma_f32_16x16x32_f16(af, v_cur1, acc1, 0, 0, 0);
        acc2 = __builtin_amdgcn_mfma_f32_16x16x32_f16(af, v_cur2, acc2, 0, 0, 0);
        acc3 = __builtin_amdgcn_mfma_f32_16x16x32_f16(af, v_cur3, acc3, 0, 0, 0);
        accd = __builtin_amdgcn_mfma_f32_16x16x32_f16(af, bones,  accd, 0, 0, 0);

        v_cur0 = v_nxt0; v_cur1 = v_nxt1; v_cur2 = v_nxt2; v_cur3 = v_nxt3;
        LOAD_V(tn, v_nxt0, v_nxt1, v_nxt2, v_nxt3);
    }
#undef LOAD_A
#undef LOAD_V

    // epilogue: C layout col=lane&15 (f), row=q*4+reg (i) -> aligned float4 stores
    float* aggb = aggT + ((size_t)(p * B_ + b)) * 256 * N_;
    const int ibase = i0 + q * 4;
    {
        int k = w * 64 + 0  + m; *(floatx4*)(aggb + (size_t)k * N_ + ibase) = acc0;
    }
    {
        int k = w * 64 + 16 + m; *(floatx4*)(aggb + (size_t)k * N_ + ibase) = acc1;
    }
    {
        int k = w * 64 + 32 + m; *(floatx4*)(aggb + (size_t)k * N_ + ibase) = acc2;
    }
    {
        int k = w * 64 + 48 + m; *(floatx4*)(aggb + (size_t)k * N_ + ibase) = acc3;
    }
    if (m == 0) {
        *(floatx4*)(degT + ((size_t)((p * B_ + b) * L_ + w)) * N_ + ibase) = accd;
    }
}

// ---------------------------------------------------------------------------
// K2: out[b,i,c] = sigmoid(V@w1 + (deg (x) V)@w2 - agg@w3), fp32 VALU.
// grid = B * N/4 = 1024 blocks (4/CU, 16 waves/CU), 256 thr.
// Block = 4 i-rows x 64 c.  Phase 1: cooperative coalesced loads sum the SK
// agg/deg partials into LDS.  Phase 2: thread=(i,c); weight loads coalesced
// over c, x-operands are LDS broadcasts.
// ---------------------------------------------------------------------------
__global__ __launch_bounds__(256) void k2_out(const float* __restrict__ V,
                                              const float* __restrict__ degT,
                                              const float* __restrict__ aggT,
                                              const float* __restrict__ w1,
                                              const float* __restrict__ w2,
                                              const float* __restrict__ w3,
                                              float* __restrict__ out) {
    __shared__ float xsum[256][4];   // [k][i_loc]  summed agg partials
    __shared__ float vt[4][64];      // [i_loc][f]
    __shared__ float dsum[4][4];     // [l][i_loc]  summed deg partials

    const int raw = blockIdx.x;      // 0..1023
    const int b   = raw >> 9;
    const int t9  = raw & 511;
    // XCD swizzle: consecutive-i tiles land on the same XCD (L2 line sharing
    // for the 16B/lane agg reads). tile = (t9&7)*64 + (t9>>3) is a bijection.
    const int tile = ((t9 & 7) << 6) | (t9 >> 3);
    const int i0  = tile * 4;
    const int tid = threadIdx.x;

    // phase 1a: xsum[k][0..3] = sum_p aggT[p][b][k][i0..i0+3]
    {
        const int k = tid;
        const float* g = aggT + ((size_t)b * 256 + k) * N_ + i0;
        const size_t PS = (size_t)B_ * 256 * N_;
        floatx4 s = *(const floatx4*)(g);
        s += *(const floatx4*)(g + PS);
        s += *(const floatx4*)(g + 2 * PS);
        s += *(const floatx4*)(g + 3 * PS);
        *(floatx4*)&xsum[k][0] = s;
    }
    // phase 1b: vt[i_loc][f] (coalesced 1 KB)
    {
        const int il = tid >> 6, f = tid & 63;
        vt[il][f] = V[((size_t)(b * N_ + i0 + il)) * F_ + f];
    }
    // phase 1c: dsum[l][i_loc]
    if (tid < 16) {
        const int l = tid >> 2, il = tid & 3;
        float s = 0.0f;
#pragma unroll
        for (int p = 0; p < SK; ++p)
            s += degT[((size_t)((p * B_ + b) * L_ + l)) * N_ + i0 + il];
        dsum[l][il] = s;
    }
    __syncthreads();

    // phase 2: one thread per (i_loc, c); wave = one i row (LDS reads broadcast)
    const int il = tid >> 6;
    const int c  = tid & 63;
    const float d0 = dsum[0][il], d1 = dsum[1][il], d2 = dsum[2][il], d3 = dsum[3][il];

    float acc = 0.0f;
#pragma unroll 4
    for (int f = 0; f < 64; ++f) {
        const float x = vt[il][f];
        acc += x        * w1[f * 64 + c];
        acc += (d0 * x) * w2[(0 * 64 + f) * 64 + c];
        acc += (d1 * x) * w2[(1 * 64 + f) * 64 + c];
        acc += (d2 * x) * w2[(2 * 64 + f) * 64 + c];
        acc += (d3 * x) * w2[(3 * 64 + f) * 64 + c];
    }
#pragma unroll 4
    for (int k = 0; k < 256; ++k) {
        acc -= xsum[k][il] * w3[k * 64 + c];
    }

    out[((size_t)(b * N_ + i0 + il)) * C_ + c] = 1.0f / (1.0f + __expf(-acc));
}

// ---------------------------------------------------------------------------
extern "C" void kernel_launch(void* const* d_in, const int* in_sizes, int n_in,
                              void* d_out, int out_size, void* d_ws, size_t ws_size,
                              hipStream_t stream) {
    const float* V  = (const float*)d_in[0];
    const float* A  = (const float*)d_in[1];
    const float* w1 = (const float*)d_in[2];
    const float* w2 = (const float*)d_in[3];
    const float* w3 = (const float*)d_in[4];
    float* out = (float*)d_out;

    char* ws = (char*)d_ws;
    float*    aggT = (float*)(ws);                  // SK*B*256*N*4 = 16 MB
    float*    degT = (float*)(ws + 16777216);       // SK*B*L*N*4   = 256 KB
    _Float16* Vth  = (_Float16*)(ws + 17039360);    // B*F*N*2      = 512 KB

    hipLaunchKernelGGL(k0_transpose, dim3(B_ * (N_ / 64)), dim3(256), 0, stream, V, Vth);
    hipLaunchKernelGGL(k1_agg,       dim3(B_ * (N_ / 16) * SK), dim3(256), 0, stream,
                       A, Vth, aggT, degT);
    hipLaunchKernelGGL(k2_out,       dim3(B_ * (N_ / 4)), dim3(256), 0, stream,
                       V, degT, aggT, w1, w2, w3, out);
}